// Round 11
// baseline (32739.917 us; speedup 1.0000x reference)
//
#include <hip/hip_runtime.h>

#define TT    8192
#define HD    1024
#define NBLK  256       // compute blocks; block NBLK is the dedicated sequencer
#define NTHR  256
#define NBUF  4         // pair-ring depth — safety proof below
#define NREP  8         // flag replicas, one 64B line each
#define KSPEC 4         // bounded speculative attempts before flag fallback

typedef int i32x4 __attribute__((ext_vector_type(4)));
typedef int i32x2 __attribute__((ext_vector_type(2)));

// ---- LLC-coherent accesses (sc0 sc1 = bypass L1+L2, coherent at MALL) ----
__device__ __forceinline__ void llc_load_pair(const unsigned* p, i32x4& a, i32x4& b) {
  asm volatile("global_load_dwordx4 %0, %2, off sc0 sc1\n\t"
               "global_load_dwordx4 %1, %3, off sc0 sc1\n\t"
               "s_waitcnt vmcnt(0)"
               : "=&v"(a), "=&v"(b)
               : "v"(p), "v"(p + 4)
               : "memory");
}
__device__ __forceinline__ unsigned llc_load1(const unsigned* p) {
  unsigned r;
  asm volatile("global_load_dword %0, %1, off sc0 sc1\n\ts_waitcnt vmcnt(0)"
               : "=v"(r) : "v"(p) : "memory");
  return r;
}
__device__ __forceinline__ void llc_store2(unsigned* p, unsigned lo, unsigned hi) {
  i32x2 v; v.x = (int)lo; v.y = (int)hi;
  asm volatile("global_store_dwordx2 %0, %1, off sc0 sc1"
               :: "v"(p), "v"(v) : "memory");
}
__device__ __forceinline__ void llc_store1(unsigned* p, unsigned v) {
  asm volatile("global_store_dword %0, %1, off sc0 sc1"
               :: "v"(p), "v"(v) : "memory");
}

__device__ __forceinline__ float sigf(float z) {
  return 1.0f / (1.0f + __expf(-z));
}
__device__ __forceinline__ float tanh_fast(float z) {
  float az = fabsf(z);
  float e  = __expf(2.0f * az);          // >= 1
  float t  = 1.0f - 2.0f / (e + 1.0f);
  return z < 0.0f ? -t : t;
}

#define FMA4(acc, hvv, wvv)                                      \
  acc = fmaf((hvv).x, (wvv).x, acc);                             \
  acc = fmaf((hvv).y, (wvv).y, acc);                             \
  acc = fmaf((hvv).z, (wvv).z, acc);                             \
  acc = fmaf((hvv).w, (wvv).w, acc);

// hbuf: unsigned[NBUF][HD][2] {value_bits, tag}; h of step t -> ring t%NBUF,
// tag t+1 (single 8-B store: tag certifies value).
//
// GATHER (new): each thread first tries KSPEC SPECULATIVE self-verified
// reads of its 4 pairs — the read that sees tags==t already carries the
// data (single hop, ~1 RTT).  Only on KSPEC misses does it fall back to the
// R0 path: poll the sequencer-certified flag replica, then one certified
// read.  Bounded retries cap poll traffic (~2 MB/round, <=5 rounds/step),
// avoiding the R2 unbounded-poll equilibrium (17 MB/step, inflated RTT).
// Own-block h values come from an LDS stash — no global self-read race.
//
// SEQUENCER: unchanged topology, but predicate is tag >= want (tags are
// monotone per slot: t+1, t+5, ...), so producers running ahead of the
// sequencer can never wedge it.  flag >= t still certifies "every unit
// stored h_{t-1} at some past time".
//
// RING SAFETY (NBUF=4, mixed spec/fallback): a block reaches step t only
// after verifying (spec or flag) all tags of h_{t-1}, i.e. every block
// passed step t-1, i.e. (induction) every block's step-(t-3) reads of slot
// t%4 completed (each read ends s_waitcnt vmcnt(0)) before any step-t
// overwrite of that slot.  Max inter-block skew is 1 step (verification
// blocks on the laggard), so a fallback reader at step t cannot see its
// slot (t-1)%4 overwritten (that requires a block at step t+3).  QED.
//
// PROJECTION: out[t] = sum over blocks of <own 4 h values, W_fc rows> via
// one fire-and-forget f32 atomicAdd per block per step (out pre-zeroed by
// the launcher).  Removes the asymmetric rotating-block tail that would
// desynchronize the speculative equilibrium; all 256 blocks are
// timing-identical.
extern "C" __global__ __launch_bounds__(NTHR, 1)
void lstm_persistent(const float* __restrict__ x,
                     const float* __restrict__ W_ih,
                     const float* __restrict__ W_hh,
                     const float* __restrict__ b_ih,
                     const float* __restrict__ b_hh,
                     const float* __restrict__ W_fc,
                     const float* __restrict__ b_fc,
                     float* __restrict__ out,
                     unsigned* __restrict__ flag,
                     unsigned* __restrict__ hbuf)
{
  const int tid = threadIdx.x;
  const int blk = blockIdx.x;

  // ================= block NBLK: dedicated sequencer =====================
  if (blk == NBLK) {
    for (int t = 0; t < TT; ++t) {
      const unsigned* src = hbuf + (((t & (NBUF - 1)) * HD + tid * 4) * 2);
      i32x4 A, B;
      const unsigned want = (unsigned)(t + 1);
      do {
        llc_load_pair(src, A, B);
      } while (!((unsigned)A.y >= want && (unsigned)A.w >= want &&
                 (unsigned)B.y >= want && (unsigned)B.w >= want));
      __syncthreads();                    // all 1024 tags verified (>= want)
      if (tid < NREP)
        llc_store1(flag + (tid << 4), want);
    }
    return;
  }

  // ================= blocks 0..255: compute ==============================
  __shared__ float x_lds[TT];     // 32 KB: whole input sequence
  __shared__ float h_lds[HD];     //  4 KB: broadcast of h_{t-1}
  __shared__ float own_h[4];      // stash: this block's 4 h values of step t

  const int wave = tid >> 6;
  const int lane = tid & 63;
  const int g    = lane >> 4;     // gate 0..3 (i,f,g,o)
  const int kc   = lane & 15;     // k-chunk within the 1024-dot
  const int unit = blk * 4 + wave;

  // ---- one-time staging -------------------------------------------------
  for (int i = tid; i < TT / 4; i += NTHR)
    ((float4*)x_lds)[i] = ((const float4*)x)[i];

  // W_hh row (gate g, unit) — lane covers k = m*64 + kc*4 + {0..3}
  float4 w4[16];
  {
    const float* wr = W_hh + (size_t)(g * HD + unit) * HD + kc * 4;
#pragma unroll
    for (int m = 0; m < 16; ++m)
      w4[m] = *((const float4*)(wr + m * 64));
  }
  float wih_g[4], bs_g[4];
#pragma unroll
  for (int q = 0; q < 4; ++q) {
    int r = q * HD + unit;
    wih_g[q] = W_ih[r];
    bs_g[q]  = b_ih[r] + b_hh[r];
  }
  // projection fragment for this block (thread 0 only uses it)
  float wfco[4];
#pragma unroll
  for (int q = 0; q < 4; ++q) wfco[q] = W_fc[blk * 4 + q];
  const float bfc_add = (blk == 0) ? b_fc[0] : 0.0f;

  float c_state = 0.0f;
  __syncthreads();                // x_lds ready

  const unsigned* flag_mine = flag + ((blk & (NREP - 1)) << 4);

  // ---- the sequential scan ---------------------------------------------
  for (int t = 0; t < TT; ++t) {
    float accs = 0.0f;

    if (t > 0) {
      const unsigned want = (unsigned)t;
      float4 hv;
      if (tid == blk) {
        // own units: certified by the end-of-iteration barrier, no global read
        hv.x = own_h[0]; hv.y = own_h[1]; hv.z = own_h[2]; hv.w = own_h[3];
      } else {
        const unsigned* src =
            hbuf + (((t - 1) & (NBUF - 1)) * HD + tid * 4) * 2;
        i32x4 A, B;
        bool ok;
        int att = 0;
        do {   // speculative self-verified read: detect carries the data
          llc_load_pair(src, A, B);
          ok = ((unsigned)A.y == want && (unsigned)A.w == want &&
                (unsigned)B.y == want && (unsigned)B.w == want);
        } while (!ok && ++att < KSPEC);
        if (!ok) {
          // fallback: sequencer-certified flag, then one certified read
          while (llc_load1(flag_mine) < want) { }
          llc_load_pair(src, A, B);
        }
        hv.x = __int_as_float(A.x); hv.y = __int_as_float(A.z);
        hv.z = __int_as_float(B.x); hv.w = __int_as_float(B.z);
      }
      ((float4*)h_lds)[tid] = hv;
      __syncthreads();            // h_{t-1} broadcast complete

      // fragments + 64 FMAs (4 independent sub-chains)
      const float* hp = h_lds + kc * 4;
      float s0 = 0.f, s1 = 0.f, s2 = 0.f, s3 = 0.f;
#pragma unroll
      for (int mb = 0; mb < 4; ++mb) {
        float4 ha = *((const float4*)(hp + (mb * 4 + 0) * 64));
        float4 hb = *((const float4*)(hp + (mb * 4 + 1) * 64));
        float4 hc = *((const float4*)(hp + (mb * 4 + 2) * 64));
        float4 hd = *((const float4*)(hp + (mb * 4 + 3) * 64));
        FMA4(s0, ha, w4[mb * 4 + 0]);
        FMA4(s1, hb, w4[mb * 4 + 1]);
        FMA4(s2, hc, w4[mb * 4 + 2]);
        FMA4(s3, hd, w4[mb * 4 + 3]);
      }
      accs = (s0 + s1) + (s2 + s3);
    }

    // 4-round butterfly over kc: each 16-lane gate-group gets its gate sum
#pragma unroll
    for (int s = 1; s < 16; s <<= 1)
      accs += __shfl_xor(accs, s);

    // per-gate parallel activation (same arithmetic as serial lane-0 form)
    float xt = x_lds[t];
    float a  = accs + fmaf(xt, wih_g[g], bs_g[g]);
    float act = (g == 2) ? tanh_fast(a) : sigf(a);

    float si = __shfl(act, 0);
    float sf = __shfl(act, 16);
    float sg = __shfl(act, 32);
    float so = __shfl(act, 48);

    if (lane == 0) {
      c_state  = sf * c_state + si * sg;
      float hn = so * tanh_fast(c_state);
      llc_store2(hbuf + (((t & (NBUF - 1)) * HD + unit) * 2),
                 __float_as_uint(hn), (unsigned)(t + 1));  // fire & forget
      own_h[wave] = hn;                                    // LDS stash
    }

    __syncthreads();              // stash complete; h_lds reads done

    // projection: per-block partial dot, one fire-and-forget atomic
    if (tid == 0) {
      float part = own_h[0] * wfco[0] + own_h[1] * wfco[1] +
                   own_h[2] * wfco[2] + own_h[3] * wfco[3] + bfc_add;
      atomicAdd(out + t, part);
    }
  }
}

extern "C" void kernel_launch(void* const* d_in, const int* in_sizes, int n_in,
                              void* d_out, int out_size, void* d_ws, size_t ws_size,
                              hipStream_t stream) {
  const float* x   = (const float*)d_in[0];
  const float* Wih = (const float*)d_in[1];
  const float* Whh = (const float*)d_in[2];
  const float* bih = (const float*)d_in[3];
  const float* bhh = (const float*)d_in[4];
  const float* Wfc = (const float*)d_in[5];
  const float* bfc = (const float*)d_in[6];
  float* out = (float*)d_out;

  // ws layout: [flag: NREP lines of 64 B][hbuf: NBUF*HD tagged pairs = 32 KB]
  unsigned* flag = (unsigned*)d_ws;
  unsigned* hbuf = flag + NREP * 16;
  size_t init_bytes = (NREP * 16 + NBUF * HD * 2) * sizeof(unsigned);

  // zeros: tag 0 never equals any expected tag (>=1); flag 0 < any t
  hipMemsetAsync(d_ws, 0, init_bytes, stream);
  // out is accumulated via atomicAdd -> must start at zero
  hipMemsetAsync(d_out, 0, (size_t)TT * sizeof(float), stream);
  hipLaunchKernelGGL(lstm_persistent, dim3(NBLK + 1), dim3(NTHR), 0, stream,
                     x, Wih, Whh, bih, bhh, Wfc, bfc, out, flag, hbuf);
}

// Round 12
// 22852.570 us; speedup vs baseline: 1.4327x; 1.4327x over previous
//
#include <hip/hip_runtime.h>

#define TT    8192
#define HD    1024
#define NCB   64        // compute blocks; block NCB is the sequencer (safety net)
#define NTHR  512       // 8 waves; wave w owns units blk*16 + {2w, 2w+1}
#define NBUF  4         // ring depth; stores gated by flag >= t-2
#define NREP  8         // flag replicas, one 64B line each

typedef int i32x4 __attribute__((ext_vector_type(4)));

// ---- MALL/HBM-coherent accesses (sc0 sc1: bypass L1+L2) -------------------
__device__ __forceinline__ void llc_load4(const unsigned* p, i32x4& r) {
  asm volatile("global_load_dwordx4 %0, %1, off sc0 sc1\n\ts_waitcnt vmcnt(0)"
               : "=v"(r) : "v"(p) : "memory");
}
__device__ __forceinline__ unsigned llc_load1(const unsigned* p) {
  unsigned r;
  asm volatile("global_load_dword %0, %1, off sc0 sc1\n\ts_waitcnt vmcnt(0)"
               : "=v"(r) : "v"(p) : "memory");
  return r;
}
__device__ __forceinline__ void llc_store4(unsigned* p, unsigned a, unsigned b,
                                           unsigned c, unsigned d) {
  i32x4 v; v.x = (int)a; v.y = (int)b; v.z = (int)c; v.w = (int)d;
  asm volatile("global_store_dwordx4 %0, %1, off sc0 sc1"
               :: "v"(p), "v"(v) : "memory");
}
__device__ __forceinline__ void llc_store1(unsigned* p, unsigned v) {
  asm volatile("global_store_dword %0, %1, off sc0 sc1"
               :: "v"(p), "v"(v) : "memory");
}

__device__ __forceinline__ float sigf(float z) {
  return 1.0f / (1.0f + __expf(-z));
}
__device__ __forceinline__ float tanh_fast(float z) {
  float az = fabsf(z);
  float e  = __expf(2.0f * az);          // >= 1
  float t  = 1.0f - 2.0f / (e + 1.0f);
  return z < 0.0f ? -t : t;
}

#define FMA4(acc, hvv, wvv)                                      \
  acc = fmaf((hvv).x, (wvv).x, acc);                             \
  acc = fmaf((hvv).y, (wvv).y, acc);                             \
  acc = fmaf((hvv).z, (wvv).z, acc);                             \
  acc = fmaf((hvv).w, (wvv).w, acc);

// hbuf: unsigned[NBUF][HD][2] fused {value, tag}; h_t -> slot t%4, tag t+1.
// Producer wave publishes its 2 units as ONE 16-B store {vA,t+1,vB,t+1}.
//
// GATHER (paced self-verify — the round-12 change): every thread reads its
// ONE dwordx4 (2 fused pairs); the load that sees both tags==t carries the
// data (single hop).  On a miss it s_sleep(4) (~256 cyc) before retrying —
// pacing breaks the poll-traffic -> RTT-inflation feedback loop that sank
// rounds 2/5/6/11 (their pollers re-read continuously).  Expected rounds
// per step: ~2.  Chip-wide gather: 64 blocks x 8 KB = 512 KB/step.
//
// RING SAFETY (flag gates STORES, not reads): sequencer verifies all 1024
// tags of step s then raises flag = s+1 (so flag >= v  <=>  every unit
// stored h_{v-1}, which implies every block completed its reads of h_{v-2},
// each poll load ending s_waitcnt vmcnt(0)).  A producer stores h_t into
// slot t%4 (killing h_{t-4}) only after flag >= t-2, i.e. all reads of
// h_{t-4} completed.  In equilibrium flag lags ~1 step while the gate needs
// 2-step-old progress -> the wait never binds; the 2 flag hops leave the
// critical path entirely.  Liveness: gather needs only producer stores
// (fire & forget); flag gate needs only sequencer progress on PAST steps;
// sequencer needs only producer stores.  Acyclic.  QED.
//
// PROJECTION: per-block partial dot over its 16 units + one fire-and-forget
// f32 atomicAdd to out[t] (pre-zeroed).  Timing-symmetric across blocks.
extern "C" __global__ __launch_bounds__(NTHR, 1)
void lstm_persistent(const float* __restrict__ x,
                     const float* __restrict__ W_ih,
                     const float* __restrict__ W_hh,
                     const float* __restrict__ b_ih,
                     const float* __restrict__ b_hh,
                     const float* __restrict__ W_fc,
                     const float* __restrict__ b_fc,
                     float* __restrict__ out,
                     unsigned* __restrict__ flag,
                     unsigned* __restrict__ hbuf)
{
  const int tid  = threadIdx.x;
  const int blk  = blockIdx.x;
  const int wave = tid >> 6;
  const int lane = tid & 63;

  // ================= block NCB: sequencer (ring-safety net) ==============
  if (blk == NCB) {
    for (int t = 0; t < TT; ++t) {
      const unsigned want = (unsigned)(t + 1);
      const unsigned* src = hbuf + (size_t)(t & (NBUF - 1)) * HD * 2 + tid * 4;
      i32x4 A;
      do {                       // >= : tags are monotone, can't wedge
        llc_load4(src, A);
      } while (!((unsigned)A.y >= want && (unsigned)A.w >= want));
      __syncthreads();           // all 1024 tags verified
      if (tid < NREP)
        llc_store1(flag + (tid << 4), want);
    }
    return;
  }

  // ================= blocks 0..63: compute ===============================
  __shared__ float x_lds[TT];    // 32 KB: whole input sequence
  __shared__ float h_lds[HD];    //  4 KB: broadcast of h_{t-1}
  __shared__ float own_h[16];    // this block's 16 h values of step t

  const int g     = lane >> 4;   // gate 0..3 (i,f,g,o)
  const int kc    = lane & 15;   // k-chunk within the 1024-dot
  const int ubase = blk * 16 + 2 * wave;

  for (int i = tid; i < TT / 4; i += NTHR)
    ((float4*)x_lds)[i] = ((const float4*)x)[i];

  // W_hh rows (gate g) for units ubase, ubase+1 — lane covers
  // k = m*64 + kc*4 + {0..3}
  float4 w4a[16], w4b[16];
  {
    const float* wra = W_hh + (size_t)(g * HD + ubase) * HD + kc * 4;
    const float* wrb = wra + HD;
#pragma unroll
    for (int m = 0; m < 16; ++m) {
      w4a[m] = *((const float4*)(wra + m * 64));
      w4b[m] = *((const float4*)(wrb + m * 64));
    }
  }
  float wihA[4], bsA[4], wihB[4], bsB[4];
#pragma unroll
  for (int q = 0; q < 4; ++q) {
    int r = q * HD + ubase;
    wihA[q] = W_ih[r];     bsA[q] = b_ih[r] + b_hh[r];
    wihB[q] = W_ih[r + 1]; bsB[q] = b_ih[r + 1] + b_hh[r + 1];
  }
  // projection fragment (tid 0 uses it)
  float wfco[16];
#pragma unroll
  for (int q = 0; q < 16; ++q) wfco[q] = W_fc[blk * 16 + q];
  const float bfc_add = (blk == 0) ? b_fc[0] : 0.0f;

  float cA = 0.0f, cB = 0.0f;
  __syncthreads();               // x_lds ready

  const unsigned* flag_mine = flag + ((blk & (NREP - 1)) << 4);

  // ---- the sequential scan ----------------------------------------------
  for (int t = 0; t < TT; ++t) {
    if (t > 0) {
      // paced self-verified gather: thread reads pairs {2tid, 2tid+1}
      const unsigned want = (unsigned)t;
      const unsigned* src =
          hbuf + (size_t)((t - 1) & (NBUF - 1)) * HD * 2 + tid * 4;
      i32x4 A;
      llc_load4(src, A);
      while (!((unsigned)A.y == want && (unsigned)A.w == want)) {
        __builtin_amdgcn_s_sleep(4);     // ~256 cyc: break the poll storm
        llc_load4(src, A);
      }
      ((float2*)h_lds)[tid] =
          make_float2(__int_as_float(A.x), __int_as_float(A.z));
    }
    __syncthreads();             // h_{t-1} broadcast complete

    float accA = 0.0f, accB = 0.0f;
    if (t > 0) {
      const float* hp = h_lds + kc * 4;
      float s0a = 0.f, s1a = 0.f, s2a = 0.f, s3a = 0.f;
      float s0b = 0.f, s1b = 0.f, s2b = 0.f, s3b = 0.f;
#pragma unroll
      for (int mb = 0; mb < 4; ++mb) {
        float4 ha = *((const float4*)(hp + (mb * 4 + 0) * 64));
        float4 hc = *((const float4*)(hp + (mb * 4 + 1) * 64));
        float4 he = *((const float4*)(hp + (mb * 4 + 2) * 64));
        float4 hg = *((const float4*)(hp + (mb * 4 + 3) * 64));
        FMA4(s0a, ha, w4a[mb * 4 + 0]);  FMA4(s0b, ha, w4b[mb * 4 + 0]);
        FMA4(s1a, hc, w4a[mb * 4 + 1]);  FMA4(s1b, hc, w4b[mb * 4 + 1]);
        FMA4(s2a, he, w4a[mb * 4 + 2]);  FMA4(s2b, he, w4b[mb * 4 + 2]);
        FMA4(s3a, hg, w4a[mb * 4 + 3]);  FMA4(s3b, hg, w4b[mb * 4 + 3]);
      }
      accA = (s0a + s1a) + (s2a + s3a);
      accB = (s0b + s1b) + (s2b + s3b);
    }

    // 4-round butterfly over kc (both units)
#pragma unroll
    for (int s = 1; s < 16; s <<= 1) {
      accA += __shfl_xor(accA, s);
      accB += __shfl_xor(accB, s);
    }

    // per-gate parallel activation (16-lane groups), then combine on lane 0
    float xt = x_lds[t];
    float aA = accA + fmaf(xt, wihA[g], bsA[g]);
    float aB = accB + fmaf(xt, wihB[g], bsB[g]);
    float actA = (g == 2) ? tanh_fast(aA) : sigf(aA);
    float actB = (g == 2) ? tanh_fast(aB) : sigf(aB);

    float siA = __shfl(actA, 0),  siB = __shfl(actB, 0);
    float sfA = __shfl(actA, 16), sfB = __shfl(actB, 16);
    float sgA = __shfl(actA, 32), sgB = __shfl(actB, 32);
    float soA = __shfl(actA, 48), soB = __shfl(actB, 48);

    if (lane == 0) {
      cA = sfA * cA + siA * sgA;
      cB = sfB * cB + siB * sgB;
      float hA = soA * tanh_fast(cA);
      float hB = soB * tanh_fast(cB);
      // ring-safety gate (off critical path in equilibrium): flag >= t-2
      while (llc_load1(flag_mine) + 2u < (unsigned)t)
        __builtin_amdgcn_s_sleep(8);
      llc_store4(hbuf + ((size_t)(t & (NBUF - 1)) * HD + ubase) * 2,
                 __float_as_uint(hA), (unsigned)(t + 1),
                 __float_as_uint(hB), (unsigned)(t + 1));  // fire & forget
      own_h[2 * wave]     = hA;
      own_h[2 * wave + 1] = hB;
    }

    __syncthreads();             // stash complete; h_lds reads done

    // projection: per-block partial dot, one fire-and-forget atomic
    if (tid == 0) {
      float part = bfc_add;
#pragma unroll
      for (int q = 0; q < 16; ++q) part = fmaf(own_h[q], wfco[q], part);
      atomicAdd(out + t, part);
    }
  }
}

extern "C" void kernel_launch(void* const* d_in, const int* in_sizes, int n_in,
                              void* d_out, int out_size, void* d_ws, size_t ws_size,
                              hipStream_t stream) {
  const float* x   = (const float*)d_in[0];
  const float* Wih = (const float*)d_in[1];
  const float* Whh = (const float*)d_in[2];
  const float* bih = (const float*)d_in[3];
  const float* bhh = (const float*)d_in[4];
  const float* Wfc = (const float*)d_in[5];
  const float* bfc = (const float*)d_in[6];
  float* out = (float*)d_out;

  // ws layout: [flag: NREP lines of 64 B][hbuf: NBUF*HD tagged pairs = 32 KB]
  unsigned* flag = (unsigned*)d_ws;
  unsigned* hbuf = flag + NREP * 16;
  size_t init_bytes = (NREP * 16 + NBUF * HD * 2) * sizeof(unsigned);

  // zeros: tag 0 never equals any expected tag (>=1); flag 0 < any gate
  hipMemsetAsync(d_ws, 0, init_bytes, stream);
  // out accumulated via atomicAdd -> must start at zero
  hipMemsetAsync(d_out, 0, (size_t)TT * sizeof(float), stream);
  hipLaunchKernelGGL(lstm_persistent, dim3(NCB + 1), dim3(NTHR), 0, stream,
                     x, Wih, Whh, bih, bhh, Wfc, bfc, out, flag, hbuf);
}

// Round 13
// 20410.742 us; speedup vs baseline: 1.6041x; 1.1196x over previous
//
#include <hip/hip_runtime.h>

#define TT    8192
#define HD    1024
#define NCB   64        // compute blocks; block NCB is the sequencer (safety net)
#define NTHR  512       // 8 waves; wave w owns units blk*16 + {2w, 2w+1}
#define NBUF  8         // ring depth; stores gated by (stale) flag >= t-6
#define NREP  8         // flag replicas, one 64B line each

typedef int i32x4 __attribute__((ext_vector_type(4)));

// ---- MALL/HBM-coherent accesses (sc0 sc1: bypass L1+L2) -------------------
__device__ __forceinline__ void llc_load4(const unsigned* p, i32x4& r) {
  asm volatile("global_load_dwordx4 %0, %1, off sc0 sc1\n\ts_waitcnt vmcnt(0)"
               : "=v"(r) : "v"(p) : "memory");
}
__device__ __forceinline__ unsigned llc_load1(const unsigned* p) {
  unsigned r;
  asm volatile("global_load_dword %0, %1, off sc0 sc1\n\ts_waitcnt vmcnt(0)"
               : "=v"(r) : "v"(p) : "memory");
  return r;
}
__device__ __forceinline__ void llc_store4(unsigned* p, unsigned a, unsigned b,
                                           unsigned c, unsigned d) {
  i32x4 v; v.x = (int)a; v.y = (int)b; v.z = (int)c; v.w = (int)d;
  asm volatile("global_store_dwordx4 %0, %1, off sc0 sc1"
               :: "v"(p), "v"(v) : "memory");
}
__device__ __forceinline__ void llc_store1(unsigned* p, unsigned v) {
  asm volatile("global_store_dword %0, %1, off sc0 sc1"
               :: "v"(p), "v"(v) : "memory");
}

__device__ __forceinline__ float sigf(float z) {
  return 1.0f / (1.0f + __expf(-z));
}
__device__ __forceinline__ float tanh_fast(float z) {
  float az = fabsf(z);
  float e  = __expf(2.0f * az);          // >= 1
  float t  = 1.0f - 2.0f / (e + 1.0f);
  return z < 0.0f ? -t : t;
}

#define FMA4(acc, hvv, wvv)                                      \
  acc = fmaf((hvv).x, (wvv).x, acc);                             \
  acc = fmaf((hvv).y, (wvv).y, acc);                             \
  acc = fmaf((hvv).z, (wvv).z, acc);                             \
  acc = fmaf((hvv).w, (wvv).w, acc);

// hbuf: unsigned[NBUF][HD][2] fused {value, tag}; h_t -> slot t%8, tag t+1.
// Producer wave publishes its 2 units as ONE 16-B store {vA,t+1,vB,t+1}.
//
// GATHER (paced self-verify, r12-proven): every thread reads its ONE dwordx4
// (2 fused pairs); the load that sees both tags==t carries the data (single
// hop).  Round-13 delta: DIFFERENTIAL pacing — first retry immediate (the
// producers are near-synchronized, data usually lands within one RTT of the
// first miss), then sleep(2)~128cyc.  Cuts the barrier-max phase penalty
// (was a full 256-cyc quantum) without re-creating the r5 poll storm.
//
// STORE GATE (round-13 delta: OFF the critical path): lane0 caches the flag
// in a register.  Ring condition for NBUF=8: storing h_t (killing h_{t-8})
// is safe once flag >= t-6, because flag >= t-6  <=>  every unit stored
// h_{t-7}, which implies every block completed its vmcnt(0)-terminated
// reads of h_{t-8}.  The cached value is refreshed by a BLOCKING load at
// ITERATION START every 4th step, where it is hidden under the gather wait
// (data visibility is set by the producers' schedule; starting the poll
// late just converts a miss into a hit).  A <=4-step-stale flag ~= t-5
// always passes the >= t-6 gate in equilibrium -> zero VMEM between
// activation and publication (r12 paid ~700cyc there every step).
// Cold-start fallback: bounded poll+sleep loop (same safety as r12).
//
// SEQUENCER: unchanged (tags monotone, >= predicate, cannot wedge).
// PROJECTION: per-block partial dot + one fire-and-forget f32 atomicAdd
// (out pre-zeroed); timing-symmetric across blocks (r11-proven, absmax ok).
extern "C" __global__ __launch_bounds__(NTHR, 1)
void lstm_persistent(const float* __restrict__ x,
                     const float* __restrict__ W_ih,
                     const float* __restrict__ W_hh,
                     const float* __restrict__ b_ih,
                     const float* __restrict__ b_hh,
                     const float* __restrict__ W_fc,
                     const float* __restrict__ b_fc,
                     float* __restrict__ out,
                     unsigned* __restrict__ flag,
                     unsigned* __restrict__ hbuf)
{
  const int tid  = threadIdx.x;
  const int blk  = blockIdx.x;
  const int wave = tid >> 6;
  const int lane = tid & 63;

  // ================= block NCB: sequencer (ring-safety net) ==============
  if (blk == NCB) {
    for (int t = 0; t < TT; ++t) {
      const unsigned want = (unsigned)(t + 1);
      const unsigned* src = hbuf + (size_t)(t & (NBUF - 1)) * HD * 2 + tid * 4;
      i32x4 A;
      do {                       // >= : tags are monotone, can't wedge
        llc_load4(src, A);
      } while (!((unsigned)A.y >= want && (unsigned)A.w >= want));
      __syncthreads();           // all 1024 tags verified
      if (tid < NREP)
        llc_store1(flag + (tid << 4), want);
    }
    return;
  }

  // ================= blocks 0..63: compute ===============================
  __shared__ float x_lds[TT];    // 32 KB: whole input sequence
  __shared__ float h_lds[HD];    //  4 KB: broadcast of h_{t-1}
  __shared__ float own_h[16];    // this block's 16 h values of step t

  const int g     = lane >> 4;   // gate 0..3 (i,f,g,o)
  const int kc    = lane & 15;   // k-chunk within the 1024-dot
  const int ubase = blk * 16 + 2 * wave;

  for (int i = tid; i < TT / 4; i += NTHR)
    ((float4*)x_lds)[i] = ((const float4*)x)[i];

  // W_hh rows (gate g) for units ubase, ubase+1 — lane covers
  // k = m*64 + kc*4 + {0..3}
  float4 w4a[16], w4b[16];
  {
    const float* wra = W_hh + (size_t)(g * HD + ubase) * HD + kc * 4;
    const float* wrb = wra + HD;
#pragma unroll
    for (int m = 0; m < 16; ++m) {
      w4a[m] = *((const float4*)(wra + m * 64));
      w4b[m] = *((const float4*)(wrb + m * 64));
    }
  }
  float wihA[4], bsA[4], wihB[4], bsB[4];
#pragma unroll
  for (int q = 0; q < 4; ++q) {
    int r = q * HD + ubase;
    wihA[q] = W_ih[r];     bsA[q] = b_ih[r] + b_hh[r];
    wihB[q] = W_ih[r + 1]; bsB[q] = b_ih[r + 1] + b_hh[r + 1];
  }
  // projection fragment (tid 0 uses it)
  float wfco[16];
#pragma unroll
  for (int q = 0; q < 16; ++q) wfco[q] = W_fc[blk * 16 + q];
  const float bfc_add = (blk == 0) ? b_fc[0] : 0.0f;

  float cA = 0.0f, cB = 0.0f;
  unsigned fl = 0;               // lane0s' cached flag (stale-tolerant)
  __syncthreads();               // x_lds ready

  const unsigned* flag_mine = flag + ((blk & (NREP - 1)) << 4);

  // ---- the sequential scan ----------------------------------------------
  for (int t = 0; t < TT; ++t) {
    if (t > 0) {
      // opportunistic flag refresh, hidden under the gather wait
      if (lane == 0 && (t & 3) == 0)
        fl = llc_load1(flag_mine);

      // paced self-verified gather: thread reads pairs {2tid, 2tid+1}
      const unsigned want = (unsigned)t;
      const unsigned* src =
          hbuf + (size_t)((t - 1) & (NBUF - 1)) * HD * 2 + tid * 4;
      i32x4 A;
      llc_load4(src, A);
      if (!((unsigned)A.y == want && (unsigned)A.w == want)) {
        llc_load4(src, A);                   // immediate retry (cheap, 1 RTT)
        while (!((unsigned)A.y == want && (unsigned)A.w == want)) {
          __builtin_amdgcn_s_sleep(2);       // ~128 cyc: paced thereafter
          llc_load4(src, A);
        }
      }
      ((float2*)h_lds)[tid] =
          make_float2(__int_as_float(A.x), __int_as_float(A.z));
    }
    __syncthreads();             // h_{t-1} broadcast complete

    float accA = 0.0f, accB = 0.0f;
    if (t > 0) {
      const float* hp = h_lds + kc * 4;
      float s0a = 0.f, s1a = 0.f, s2a = 0.f, s3a = 0.f;
      float s0b = 0.f, s1b = 0.f, s2b = 0.f, s3b = 0.f;
#pragma unroll
      for (int mb = 0; mb < 4; ++mb) {
        float4 ha = *((const float4*)(hp + (mb * 4 + 0) * 64));
        float4 hc = *((const float4*)(hp + (mb * 4 + 1) * 64));
        float4 he = *((const float4*)(hp + (mb * 4 + 2) * 64));
        float4 hg = *((const float4*)(hp + (mb * 4 + 3) * 64));
        FMA4(s0a, ha, w4a[mb * 4 + 0]);  FMA4(s0b, ha, w4b[mb * 4 + 0]);
        FMA4(s1a, hc, w4a[mb * 4 + 1]);  FMA4(s1b, hc, w4b[mb * 4 + 1]);
        FMA4(s2a, he, w4a[mb * 4 + 2]);  FMA4(s2b, he, w4b[mb * 4 + 2]);
        FMA4(s3a, hg, w4a[mb * 4 + 3]);  FMA4(s3b, hg, w4b[mb * 4 + 3]);
      }
      accA = (s0a + s1a) + (s2a + s3a);
      accB = (s0b + s1b) + (s2b + s3b);
    }

    // 4-round butterfly over kc (both units)
#pragma unroll
    for (int s = 1; s < 16; s <<= 1) {
      accA += __shfl_xor(accA, s);
      accB += __shfl_xor(accB, s);
    }

    // per-gate parallel activation (16-lane groups), then combine on lane 0
    float xt = x_lds[t];
    float aA = accA + fmaf(xt, wihA[g], bsA[g]);
    float aB = accB + fmaf(xt, wihB[g], bsB[g]);
    float actA = (g == 2) ? tanh_fast(aA) : sigf(aA);
    float actB = (g == 2) ? tanh_fast(aB) : sigf(aB);

    float siA = __shfl(actA, 0),  siB = __shfl(actB, 0);
    float sfA = __shfl(actA, 16), sfB = __shfl(actB, 16);
    float sgA = __shfl(actA, 32), sgB = __shfl(actB, 32);
    float soA = __shfl(actA, 48), soB = __shfl(actB, 48);

    if (lane == 0) {
      cA = sfA * cA + siA * sgA;
      cB = sfB * cB + siB * sgB;
      float hA = soA * tanh_fast(cA);
      float hB = soB * tanh_fast(cB);
      // ring-safety gate: stale cached flag, zero VMEM in equilibrium
      while (fl + 6u < (unsigned)t) {        // cold-start fallback only
        __builtin_amdgcn_s_sleep(4);
        fl = llc_load1(flag_mine);
      }
      llc_store4(hbuf + ((size_t)(t & (NBUF - 1)) * HD + ubase) * 2,
                 __float_as_uint(hA), (unsigned)(t + 1),
                 __float_as_uint(hB), (unsigned)(t + 1));  // fire & forget
      own_h[2 * wave]     = hA;
      own_h[2 * wave + 1] = hB;
    }

    __syncthreads();             // stash complete; h_lds reads done

    // projection: per-block partial dot, one fire-and-forget atomic
    if (tid == 0) {
      float part = bfc_add;
#pragma unroll
      for (int q = 0; q < 16; ++q) part = fmaf(own_h[q], wfco[q], part);
      atomicAdd(out + t, part);
    }
  }
}

extern "C" void kernel_launch(void* const* d_in, const int* in_sizes, int n_in,
                              void* d_out, int out_size, void* d_ws, size_t ws_size,
                              hipStream_t stream) {
  const float* x   = (const float*)d_in[0];
  const float* Wih = (const float*)d_in[1];
  const float* Whh = (const float*)d_in[2];
  const float* bih = (const float*)d_in[3];
  const float* bhh = (const float*)d_in[4];
  const float* Wfc = (const float*)d_in[5];
  const float* bfc = (const float*)d_in[6];
  float* out = (float*)d_out;

  // ws layout: [flag: NREP lines of 64 B][hbuf: NBUF*HD tagged pairs = 64 KB]
  unsigned* flag = (unsigned*)d_ws;
  unsigned* hbuf = flag + NREP * 16;
  size_t init_bytes = (NREP * 16 + NBUF * HD * 2) * sizeof(unsigned);

  // zeros: tag 0 never equals any expected tag (>=1); flag 0 < any gate
  hipMemsetAsync(d_ws, 0, init_bytes, stream);
  // out accumulated via atomicAdd -> must start at zero
  hipMemsetAsync(d_out, 0, (size_t)TT * sizeof(float), stream);
  hipLaunchKernelGGL(lstm_persistent, dim3(NCB + 1), dim3(NTHR), 0, stream,
                     x, Wih, Whh, bih, bhh, Wfc, bfc, out, flag, hbuf);
}